// Round 1
// baseline (358.544 us; speedup 1.0000x reference)
//
#include <hip/hip_runtime.h>
#include <math.h>

// Problem constants (from reference)
#define NA 3
#define NC 80
#define CH 85              // NC+5
#define NB 16
#define HH 52
#define WW 52
#define HW 2704            // HH*WW
#define NT 256             // num targets
#define NCELLS (NB*NA*HW)  // 129792
#define STRIDE_F 8.0f      // 416/52
#define IGN_THR 0.5f

struct TRec {
    int img, best, gi, gj, label, ignbits;
    float tx, ty, tw, th;
};

__device__ __forceinline__ float sigm(float z) { return 1.0f / (1.0f + expf(-z)); }
// -log(sigmoid(z)) = log1p(exp(-z));  -log(1-sigmoid(z)) = log1p(exp(z))
__device__ __forceinline__ float splus(float z) { return log1pf(expf(z)); }

// ---------------------------------------------------------------------------
// Kernel A: per-target records + zero the accumulator (ws is poisoned 0xAA).
// ---------------------------------------------------------------------------
__global__ __launch_bounds__(256) void targets_kernel(
        const float* __restrict__ target, float* __restrict__ acc,
        TRec* __restrict__ recs) {
    int n = threadIdx.x;
    if (n < 16) acc[n] = 0.0f;
    if (n >= NT) return;
    const float awc[3] = {10.f, 16.f, 33.f};
    const float ahc[3] = {13.f, 30.f, 23.f};
    float timg = target[n*6 + 0];
    float gxc  = target[n*6 + 1] * (float)WW;
    float gyc  = target[n*6 + 2] * (float)HH;
    float gw   = target[n*6 + 3] * (float)WW;
    float gh   = target[n*6 + 4] * (float)HH;
    int label  = (int)target[n*6 + 5];

    float best_iou = -1.0f;
    int best = 0, ignbits = 0;
    for (int a = 0; a < 3; a++) {
        float inter = fminf(awc[a], gw) * fminf(ahc[a], gh);
        float iou = inter / (awc[a]*ahc[a] + 1e-16f + gw*gh - inter);
        if (iou > best_iou) { best_iou = iou; best = a; }   // first-max argmax
        if (iou > IGN_THR) ignbits |= (1 << a);
    }
    TRec r;
    r.img = (int)timg; r.best = best;
    r.gi = (int)gxc;   r.gj = (int)gyc;
    r.label = label;   r.ignbits = ignbits;
    r.tx = gxc - floorf(gxc);
    r.ty = gyc - floorf(gyc);
    r.tw = logf(gw / awc[best] + 1e-16f);
    r.th = logf(gh / ahc[best] + 1e-16f);
    recs[n] = r;
}

// ---------------------------------------------------------------------------
// Kernel B (main): dense transform x -> output via LDS transpose, and the
// dense part of the noobj BCE sum (softplus of conf channel, all cells).
// Grid: (43 pixel-chunks of 64, 48 = B*A).  Block: 256.
// ---------------------------------------------------------------------------
__global__ __launch_bounds__(256) void main_kernel(
        const float* __restrict__ x, float* __restrict__ out,
        float* __restrict__ acc) {
    __shared__ float lds[CH * 65];   // pad 64->65 breaks phase-2 bank conflicts
    __shared__ float red[4];
    int chunk = blockIdx.x;          // 0..42
    int ba    = blockIdx.y;          // 0..47  (= b*3 + a)
    int a     = ba % NA;
    int p0    = chunk * 64;
    int ncells = min(64, HW - p0);   // 64, tail chunk = 16
    int t  = threadIdx.x;
    int c0 = t >> 6;                 // 0..3: channel phase
    int lc = t & 63;                 // cell within chunk
    bool valid = lc < ncells;
    int pix = p0 + lc;

    float noobj_local = 0.0f;
    if (valid) {
        int wc = pix % WW, hc = pix / WW;
        const float awc[3] = {10.f, 16.f, 33.f};
        const float ahc[3] = {13.f, 30.f, 23.f};
        const float* xp = x + (size_t)(ba * CH) * HW + pix;
        for (int c = c0; c < CH; c += 4) {
            float v = xp[(size_t)c * HW];  // coalesced: lanes = consecutive pix
            float o;
            if (c == 0)      o = (sigm(v) + (float)wc) * STRIDE_F;
            else if (c == 1) o = (sigm(v) + (float)hc) * STRIDE_F;
            else if (c == 2) o = expf(v) * awc[a];
            else if (c == 3) o = expf(v) * ahc[a];
            else {
                o = sigm(v);
                if (c == 4) noobj_local += splus(v);  // -log(1-pconf)
            }
            lds[c * 65 + lc] = o;
        }
    }
    __syncthreads();

    // Phase 2: coalesced write of [cell][channel]-ordered output
    int nelem = ncells * CH;
    size_t obase = (size_t)(ba * HW + p0) * CH;
    for (int f = t; f < nelem; f += 256) {
        int cell = f / CH;
        int ch = f - cell * CH;
        out[obase + f] = lds[ch * 65 + cell];
    }

    // Reduce the noobj partial (only c0==0 threads are nonzero)
    for (int off = 32; off > 0; off >>= 1)
        noobj_local += __shfl_down(noobj_local, off, 64);
    if ((t & 63) == 0) red[t >> 6] = noobj_local;
    __syncthreads();
    if (t == 0) atomicAdd(&acc[0], red[0] + red[1] + red[2] + red[3]);
}

// ---------------------------------------------------------------------------
// Kernel C (finish): sparse obj losses + noobj corrections + final scalar.
// Single block, 256 threads (= NT).
// ---------------------------------------------------------------------------
__global__ __launch_bounds__(256) void finish_kernel(
        const float* __restrict__ x, const TRec* __restrict__ recs,
        const float* __restrict__ acc, float* __restrict__ out_total) {
    __shared__ int s_keyobj[NT];
    __shared__ int s_zkey[NT * 3];
    __shared__ unsigned char s_zflag[NT * 3];
    __shared__ float r[256];
    __shared__ float totals[9];
    int t = threadIdx.x;

    TRec rec = recs[t];
    int cellbase = rec.img * (NA * HW) + rec.gj * WW + rec.gi;
    int keyobj = cellbase + rec.best * HW;
    s_keyobj[t] = keyobj;
    for (int a = 0; a < 3; a++) {
        s_zkey[t*3 + a]  = cellbase + a * HW;
        s_zflag[t*3 + a] = (unsigned char)((a == rec.best) || ((rec.ignbits >> a) & 1));
    }
    __syncthreads();

    // Last-writer-wins scatter semantics: target n owns its cell iff no later
    // target m>n maps to the same (img,best,gj,gi).
    bool winner = true;
    for (int m = t + 1; m < NT; m++)
        if (s_keyobj[m] == keyobj) { winner = false; break; }

    float lx=0, ly=0, lw=0, lh=0, lco=0, lcls=0, lnobj=0, lcount=0, lucount=0;
    if (winner) {
        lcount = 1.0f;
        const float* xp = x + (size_t)((rec.img * NA + rec.best) * CH) * HW
                            + rec.gj * WW + rec.gi;
        float z0 = xp[0];
        float cx = sigm(z0);
        lx = (cx - rec.tx) * (cx - rec.tx);
        ly = (cx - rec.ty) * (cx - rec.ty);   // reference bug: cx used for y loss
        float z2 = xp[(size_t)2 * HW];
        lw = (z2 - rec.tw) * (z2 - rec.tw);
        lh = (z2 - rec.th) * (z2 - rec.th);   // reference bug: pw used for h loss
        float z4 = xp[(size_t)4 * HW];
        lco = splus(-z4);                      // -log(pconf), t=1
        for (int c = 0; c < NC; c++) {
            float z = xp[(size_t)(5 + c) * HW];
            lcls += (c == rec.label) ? splus(-z) : splus(z);
        }
    }

    // Distinct zeroed-noobj cells: subtract their -log(1-pconf) from the dense
    // sum and count them (n_noobj = NCELLS - count).  First-occurrence dedupe.
    for (int e = t; e < NT * 3; e += 256) {
        if (!s_zflag[e]) continue;
        int key = s_zkey[e];
        bool first = true;
        for (int e2 = 0; e2 < e; e2++)
            if (s_zflag[e2] && s_zkey[e2] == key) { first = false; break; }
        if (first) {
            lucount += 1.0f;
            int imga = key / HW;             // img*3 + a
            int pixel = key - imga * HW;
            float z4 = x[(size_t)(imga * CH + 4) * HW + pixel];
            lnobj += splus(z4);
        }
    }

    // Block reductions of the 9 partials
    float vals[9] = {lx, ly, lw, lh, lco, lcls, lnobj, lcount, lucount};
    for (int q = 0; q < 9; q++) {
        __syncthreads();
        r[t] = vals[q];
        __syncthreads();
        for (int s = 128; s > 0; s >>= 1) {
            if (t < s) r[t] += r[t + s];
            __syncthreads();
        }
        if (t == 0) totals[q] = r[0];
    }
    __syncthreads();

    if (t == 0) {
        float sx = totals[0], sy = totals[1], sw = totals[2], sh = totals[3];
        float sco = totals[4], scls = totals[5], snobj = totals[6];
        float n_obj_raw = totals[7], ucount = totals[8];
        float n_obj = fmaxf(n_obj_raw, 1.0f);
        float n_noobj = fmaxf((float)NCELLS - ucount, 1.0f);
        float noobj_sum = acc[0] - snobj;
        float total = sx / n_obj + sy / n_obj + sw / n_obj + sh / n_obj
                    + 1.0f * (sco / n_obj)               // OBJ_SCALE * obj BCE
                    + 0.5f * (noobj_sum / n_noobj)       // NOOBJ_SCALE * noobj BCE
                    + scls / fmaxf(80.0f * n_obj_raw, 1.0f);
        out_total[0] = total;
    }
}

// ---------------------------------------------------------------------------
extern "C" void kernel_launch(void* const* d_in, const int* in_sizes, int n_in,
                              void* d_out, int out_size, void* d_ws, size_t ws_size,
                              hipStream_t stream) {
    (void)in_sizes; (void)n_in; (void)out_size; (void)ws_size;
    const float* x      = (const float*)d_in[0];
    const float* target = (const float*)d_in[1];
    float* out = (float*)d_out;
    float* acc = (float*)d_ws;                       // 16 floats
    TRec*  recs = (TRec*)((char*)d_ws + 64);         // 256 records (~10 KB)

    targets_kernel<<<1, 256, 0, stream>>>(target, acc, recs);
    dim3 grid(43, 48);                               // 43 chunks x (B*A)
    main_kernel<<<grid, 256, 0, stream>>>(x, out, acc);
    finish_kernel<<<1, 256, 0, stream>>>(x, recs, acc,
                                         out + (size_t)NB * NA * HW * CH);
}

// Round 2
// 307.339 us; speedup vs baseline: 1.1666x; 1.1666x over previous
//
#include <hip/hip_runtime.h>
#include <math.h>

// Problem constants (from reference)
#define NA 3
#define NC 80
#define CH 85              // NC+5
#define NB 16
#define HH 52
#define WW 52
#define HW 2704            // HH*WW
#define NT 256             // num targets
#define NCELLS (NB*NA*HW)  // 129792
#define STRIDE_F 8.0f      // 416/52
#define IGN_THR 0.5f

__device__ __forceinline__ float sigm(float z) { return 1.0f / (1.0f + expf(-z)); }
// -log(sigmoid(z)) = log1p(exp(-z));  -log(1-sigmoid(z)) = log1p(exp(z))
__device__ __forceinline__ float splus(float z) { return log1pf(expf(z)); }

// ws layout (bytes):
//   0    : float acc[16]   acc[0]=dense noobj sum, acc[1]=obj xywh+conf sum,
//                          acc[2]=cls sum, acc[3]=zeroed-cell noobj correction
//   64   : int cnts[2]     {wcount, zcount}
//   128  : int   wofs[256]
//   1152 : float wtx[256]
//   2176 : float wty[256]
//   3200 : float wtw[256]
//   4224 : float wth[256]
//   5248 : int   wlabel[256]
//   6272 : int   zofs[768]
// total 9344 B

// ---------------------------------------------------------------------------
// Kernel A (prep): single block. Target records + winner (last-writer-wins)
// dedupe + zeroed-noobj-cell first-occurrence dedupe -> compact lists.
// No x reads. LDS only.
// ---------------------------------------------------------------------------
__global__ __launch_bounds__(256) void prep_kernel(
        const float* __restrict__ target, float* __restrict__ acc,
        int* __restrict__ cnts, int* __restrict__ wofs,
        float* __restrict__ wtx, float* __restrict__ wty,
        float* __restrict__ wtw, float* __restrict__ wth,
        int* __restrict__ wlabel, int* __restrict__ zofs) {
    __shared__ int s_keyobj[NT];
    __shared__ int s_zkey[NT * 3];
    __shared__ unsigned char s_zflag[NT * 3];
    __shared__ int s_wcnt, s_zcnt;
    int t = threadIdx.x;
    if (t < 16) acc[t] = 0.0f;
    if (t == 0) { s_wcnt = 0; s_zcnt = 0; }

    const float awc[3] = {10.f, 16.f, 33.f};
    const float ahc[3] = {13.f, 30.f, 23.f};
    float timg = target[t*6 + 0];
    float gxc  = target[t*6 + 1] * (float)WW;
    float gyc  = target[t*6 + 2] * (float)HH;
    float gw   = target[t*6 + 3] * (float)WW;
    float gh   = target[t*6 + 4] * (float)HH;
    int label  = (int)target[t*6 + 5];

    float best_iou = -1.0f;
    int best = 0, ignbits = 0;
    for (int a = 0; a < 3; a++) {
        float inter = fminf(awc[a], gw) * fminf(ahc[a], gh);
        float iou = inter / (awc[a]*ahc[a] + 1e-16f + gw*gh - inter);
        if (iou > best_iou) { best_iou = iou; best = a; }   // first-max argmax
        if (iou > IGN_THR) ignbits |= (1 << a);
    }
    int img = (int)timg;
    int gi = (int)gxc, gj = (int)gyc;
    int cellbase = img * (NA * HW) + gj * WW + gi;
    int keyobj = cellbase + best * HW;
    s_keyobj[t] = keyobj;
    for (int a = 0; a < 3; a++) {
        s_zkey[t*3 + a]  = cellbase + a * HW;
        s_zflag[t*3 + a] = (unsigned char)((a == best) || ((ignbits >> a) & 1));
    }
    __syncthreads();

    // winner iff no later target maps to same (img,best,gj,gi)
    bool winner = true;
    for (int m = t + 1; m < NT; m++)
        if (s_keyobj[m] == keyobj) { winner = false; break; }
    if (winner) {
        int p = atomicAdd(&s_wcnt, 1);
        wofs[p] = (img * NA + best) * (CH * HW) + gj * WW + gi;
        wtx[p] = gxc - floorf(gxc);
        wty[p] = gyc - floorf(gyc);
        wtw[p] = logf(gw / awc[best] + 1e-16f);
        wth[p] = logf(gh / ahc[best] + 1e-16f);
        wlabel[p] = label;
    }

    // distinct zeroed-noobj cells (first occurrence wins; order irrelevant)
    for (int e = t; e < NT * 3; e += 256) {
        if (!s_zflag[e]) continue;
        int key = s_zkey[e];
        bool first = true;
        for (int e2 = 0; e2 < e; e2++)
            if (s_zflag[e2] && s_zkey[e2] == key) { first = false; break; }
        if (first) {
            int p = atomicAdd(&s_zcnt, 1);
            int imga = key / HW;            // img*3 + a
            int pixel = key - imga * HW;
            zofs[p] = (imga * CH + 4) * HW + pixel;
        }
    }
    __syncthreads();
    if (t == 0) { cnts[0] = s_wcnt; cnts[1] = s_zcnt; }
}

// ---------------------------------------------------------------------------
// Kernel B (main): dense transform x -> output via LDS transpose, and the
// dense part of the noobj BCE sum (softplus of conf channel, all cells).
// Grid: (43 pixel-chunks of 64, 48 = B*A).  Block: 256.
// ---------------------------------------------------------------------------
__global__ __launch_bounds__(256) void main_kernel(
        const float* __restrict__ x, float* __restrict__ out,
        float* __restrict__ acc) {
    __shared__ float lds[CH * 65];   // pad 64->65 breaks phase-2 bank conflicts
    __shared__ float red[4];
    int chunk = blockIdx.x;          // 0..42
    int ba    = blockIdx.y;          // 0..47  (= b*3 + a)
    int a     = ba % NA;
    int p0    = chunk * 64;
    int ncells = min(64, HW - p0);   // 64, tail chunk = 16
    int t  = threadIdx.x;
    int c0 = t >> 6;                 // 0..3: channel phase
    int lc = t & 63;                 // cell within chunk
    bool valid = lc < ncells;
    int pix = p0 + lc;

    float noobj_local = 0.0f;
    if (valid) {
        int wc = pix % WW, hc = pix / WW;
        const float awc[3] = {10.f, 16.f, 33.f};
        const float ahc[3] = {13.f, 30.f, 23.f};
        const float* xp = x + (size_t)(ba * CH) * HW + pix;
        for (int c = c0; c < CH; c += 4) {
            float v = xp[(size_t)c * HW];  // coalesced: lanes = consecutive pix
            float o;
            if (c == 0)      o = (sigm(v) + (float)wc) * STRIDE_F;
            else if (c == 1) o = (sigm(v) + (float)hc) * STRIDE_F;
            else if (c == 2) o = expf(v) * awc[a];
            else if (c == 3) o = expf(v) * ahc[a];
            else {
                o = sigm(v);
                if (c == 4) noobj_local += splus(v);  // -log(1-pconf)
            }
            lds[c * 65 + lc] = o;
        }
    }
    __syncthreads();

    // Phase 2: coalesced write of [cell][channel]-ordered output
    int nelem = ncells * CH;
    size_t obase = (size_t)(ba * HW + p0) * CH;
    for (int f = t; f < nelem; f += 256) {
        int cell = f / CH;
        int ch = f - cell * CH;
        out[obase + f] = lds[ch * 65 + cell];
    }

    // Reduce the noobj partial (only c0==0 threads are nonzero)
    for (int off = 32; off > 0; off >>= 1)
        noobj_local += __shfl_down(noobj_local, off, 64);
    if ((t & 63) == 0) red[t >> 6] = noobj_local;
    __syncthreads();
    if (t == 0) atomicAdd(&acc[0], red[0] + red[1] + red[2] + red[3]);
}

// ---------------------------------------------------------------------------
// Kernel C (gather): one wave per winner cell (blocks 0..255) gathers the 85
// channel values with lanes in parallel; blocks 256.. handle zeroed cells
// one per lane.  Latency is hidden by ~268 concurrent waves chip-wide.
// ---------------------------------------------------------------------------
__global__ __launch_bounds__(64) void gather_kernel(
        const float* __restrict__ x, const int* __restrict__ cnts,
        const int* __restrict__ wofs, const float* __restrict__ wtx,
        const float* __restrict__ wty, const float* __restrict__ wtw,
        const float* __restrict__ wth, const int* __restrict__ wlabel,
        const int* __restrict__ zofs, float* __restrict__ acc) {
    int b = blockIdx.x;
    int lane = threadIdx.x;
    if (b < NT) {
        if (b >= cnts[0]) return;          // beyond winner count
        int ofs = wofs[b];
        int label = wlabel[b];
        const float* xp = x + ofs;
        float lcls = 0.0f;
        {   // class channels 0..63
            float z = xp[(size_t)(5 + lane) * HW];
            lcls += (lane == label) ? splus(-z) : splus(z);
        }
        if (lane < 16) {                   // class channels 64..79
            int c = 64 + lane;
            float z = xp[(size_t)(5 + c) * HW];
            lcls += (c == label) ? splus(-z) : splus(z);
        }
        float other = 0.0f;
        if (lane == 0) {
            float z0 = xp[0];
            float z2 = xp[(size_t)2 * HW];
            float z4 = xp[(size_t)4 * HW];
            float cx = sigm(z0);
            float dx = cx - wtx[b], dy = cx - wty[b];   // ref bug: cx for y
            float dw = z2 - wtw[b], dh = z2 - wth[b];   // ref bug: pw for h
            other = dx*dx + dy*dy + dw*dw + dh*dh + splus(-z4);
        }
        for (int off = 32; off > 0; off >>= 1)
            lcls += __shfl_down(lcls, off, 64);
        if (lane == 0) {
            atomicAdd(&acc[1], other);
            atomicAdd(&acc[2], lcls);
        }
    } else {
        int idx = (b - NT) * 64 + lane;
        float v = 0.0f;
        if (idx < cnts[1]) v = splus(x[zofs[idx]]);
        for (int off = 32; off > 0; off >>= 1)
            v += __shfl_down(v, off, 64);
        if (lane == 0 && v != 0.0f) atomicAdd(&acc[3], v);
    }
}

// ---------------------------------------------------------------------------
// Kernel D (finalize): one thread combines the accumulator slots.
// ---------------------------------------------------------------------------
__global__ void finalize_kernel(const float* __restrict__ acc,
                                const int* __restrict__ cnts,
                                float* __restrict__ out_total) {
    if (threadIdx.x == 0 && blockIdx.x == 0) {
        float wc = (float)cnts[0];
        float n_obj = fmaxf(wc, 1.0f);
        float n_noobj = fmaxf((float)NCELLS - (float)cnts[1], 1.0f);
        float cls_den = fmaxf(80.0f * wc, 1.0f);
        float noobj_sum = acc[0] - acc[3];
        out_total[0] = acc[1] / n_obj + acc[2] / cls_den
                     + 0.5f * (noobj_sum / n_noobj);
    }
}

// ---------------------------------------------------------------------------
extern "C" void kernel_launch(void* const* d_in, const int* in_sizes, int n_in,
                              void* d_out, int out_size, void* d_ws, size_t ws_size,
                              hipStream_t stream) {
    (void)in_sizes; (void)n_in; (void)out_size; (void)ws_size;
    const float* x      = (const float*)d_in[0];
    const float* target = (const float*)d_in[1];
    float* out = (float*)d_out;

    char* ws = (char*)d_ws;
    float* acc    = (float*)(ws + 0);
    int*   cnts   = (int*)  (ws + 64);
    int*   wofs   = (int*)  (ws + 128);
    float* wtx    = (float*)(ws + 1152);
    float* wty    = (float*)(ws + 2176);
    float* wtw    = (float*)(ws + 3200);
    float* wth    = (float*)(ws + 4224);
    int*   wlabel = (int*)  (ws + 5248);
    int*   zofs   = (int*)  (ws + 6272);

    prep_kernel<<<1, 256, 0, stream>>>(target, acc, cnts, wofs, wtx, wty,
                                       wtw, wth, wlabel, zofs);
    dim3 grid(43, 48);
    main_kernel<<<grid, 256, 0, stream>>>(x, out, acc);
    gather_kernel<<<NT + (NT * 3 + 63) / 64, 64, 0, stream>>>(
        x, cnts, wofs, wtx, wty, wtw, wth, wlabel, zofs, acc);
    finalize_kernel<<<1, 64, 0, stream>>>(acc, cnts,
                                          out + (size_t)NB * NA * HW * CH);
}

// Round 3
// 155.890 us; speedup vs baseline: 2.3000x; 1.9715x over previous
//
#include <hip/hip_runtime.h>
#include <math.h>

// Problem constants (from reference)
#define NA 3
#define NC 80
#define CH 85              // NC+5
#define NB 16
#define HH 52
#define WW 52
#define HW 2704            // HH*WW
#define NT 256             // num targets
#define NCELLS (NB*NA*HW)  // 129792
#define NBMW 4056          // bitmap words = ceil(NCELLS/32)
#define STRIDE_F 8.0f      // 416/52
#define IGN_THR 0.5f

__device__ __forceinline__ float sigm(float z) { return 1.0f / (1.0f + expf(-z)); }
// -log(sigmoid(z)) = log1p(exp(-z));  -log(1-sigmoid(z)) = log1p(exp(z))
__device__ __forceinline__ float splus(float z) { return log1pf(expf(z)); }

// ws layout (bytes):
//   0    : float acc[16]   acc[0]=dense noobj sum, acc[1]=obj xywh+conf sum,
//                          acc[2]=cls sum, acc[3]=zeroed-cell noobj correction
//   64   : int cnts[2]     {wcount, zcount}
//   128  : int   wofs[256]
//   1152 : float wtx[256]
//   2176 : float wty[256]
//   3200 : float wtw[256]
//   4224 : float wth[256]
//   5248 : int   wlabel[256]
//   6272 : int   zofs[768]
// total 9344 B

// ---------------------------------------------------------------------------
// Kernel A (prep): single block. Target records + winner (last-writer-wins)
// dedupe (fixed-trip pipelined LDS scan, no data-dependent break) +
// zeroed-noobj-cell dedupe via LDS bitmap atomicOr (O(1) per entry).
// R2 lesson: the previous break-on-LDS-read loops serialized at ~120 cyc
// ds_read latency -> 167 us. Both replaced with latency-tolerant forms.
// ---------------------------------------------------------------------------
__global__ __launch_bounds__(256) void prep_kernel(
        const float* __restrict__ target, float* __restrict__ acc,
        int* __restrict__ cnts, int* __restrict__ wofs,
        float* __restrict__ wtx, float* __restrict__ wty,
        float* __restrict__ wtw, float* __restrict__ wth,
        int* __restrict__ wlabel, int* __restrict__ zofs) {
    __shared__ int s_keyobj[NT];
    __shared__ unsigned int s_bm[NBMW];   // 16.2 KB cell bitmap
    __shared__ int s_wcnt, s_zcnt;
    int t = threadIdx.x;
    if (t < 16) acc[t] = 0.0f;
    if (t == 0) { s_wcnt = 0; s_zcnt = 0; }
    for (int i = t; i < NBMW; i += 256) s_bm[i] = 0u;

    const float awc[3] = {10.f, 16.f, 33.f};
    const float ahc[3] = {13.f, 30.f, 23.f};
    float timg = target[t*6 + 0];
    float gxc  = target[t*6 + 1] * (float)WW;
    float gyc  = target[t*6 + 2] * (float)HH;
    float gw   = target[t*6 + 3] * (float)WW;
    float gh   = target[t*6 + 4] * (float)HH;
    int label  = (int)target[t*6 + 5];

    float best_iou = -1.0f;
    int best = 0, ignbits = 0;
    for (int a = 0; a < 3; a++) {
        float inter = fminf(awc[a], gw) * fminf(ahc[a], gh);
        float iou = inter / (awc[a]*ahc[a] + 1e-16f + gw*gh - inter);
        if (iou > best_iou) { best_iou = iou; best = a; }   // first-max argmax
        if (iou > IGN_THR) ignbits |= (1 << a);
    }
    int img = (int)timg;
    int gi = (int)gxc, gj = (int)gyc;
    int pixel = gj * WW + gi;
    int cellbase = img * (NA * HW) + pixel;
    int keyobj = cellbase + best * HW;
    s_keyobj[t] = keyobj;
    __syncthreads();

    // winner iff no later target maps to same (img,best,gj,gi).
    // Fixed trip count, no break: 256 independent LDS reads pipeline at
    // throughput (~2-6 cyc) instead of serializing at ~120 cyc latency.
    bool dup = false;
    #pragma unroll 8
    for (int m = 0; m < NT; m++) {
        int k = s_keyobj[m];
        dup = dup || (m > t && k == keyobj);
    }
    if (!dup) {
        int p = atomicAdd(&s_wcnt, 1);
        wofs[p] = (img * NA + best) * (CH * HW) + pixel;
        wtx[p] = gxc - floorf(gxc);
        wty[p] = gyc - floorf(gyc);
        wtw[p] = logf(gw / awc[best] + 1e-16f);
        wth[p] = logf(gh / ahc[best] + 1e-16f);
        wlabel[p] = label;
    }

    // Distinct zeroed-noobj cells via bitmap: first atomicOr to set the bit
    // appends the cell (all duplicates would contribute identical offsets,
    // so which entry wins is irrelevant).
    for (int a = 0; a < 3; a++) {
        bool flag = (a == best) || ((ignbits >> a) & 1);
        if (flag) {
            int key = cellbase + a * HW;
            unsigned int bit = 1u << (key & 31);
            unsigned int old = atomicOr(&s_bm[key >> 5], bit);
            if (!(old & bit)) {
                int p = atomicAdd(&s_zcnt, 1);
                zofs[p] = ((img * NA + a) * CH + 4) * HW + pixel;
            }
        }
    }
    __syncthreads();
    if (t == 0) { cnts[0] = s_wcnt; cnts[1] = s_zcnt; }
}

// ---------------------------------------------------------------------------
// Kernel B (main): dense transform x -> output via LDS transpose, and the
// dense part of the noobj BCE sum (softplus of conf channel, all cells).
// Grid: (43 pixel-chunks of 64, 48 = B*A).  Block: 256.
// ---------------------------------------------------------------------------
__global__ __launch_bounds__(256) void main_kernel(
        const float* __restrict__ x, float* __restrict__ out,
        float* __restrict__ acc) {
    __shared__ float lds[CH * 65];   // pad 64->65 breaks phase-2 bank conflicts
    __shared__ float red[4];
    int chunk = blockIdx.x;          // 0..42
    int ba    = blockIdx.y;          // 0..47  (= b*3 + a)
    int a     = ba % NA;
    int p0    = chunk * 64;
    int ncells = min(64, HW - p0);   // 64, tail chunk = 16
    int t  = threadIdx.x;
    int c0 = t >> 6;                 // 0..3: channel phase
    int lc = t & 63;                 // cell within chunk
    bool valid = lc < ncells;
    int pix = p0 + lc;

    float noobj_local = 0.0f;
    if (valid) {
        int wc = pix % WW, hc = pix / WW;
        const float awc[3] = {10.f, 16.f, 33.f};
        const float ahc[3] = {13.f, 30.f, 23.f};
        const float* xp = x + (size_t)(ba * CH) * HW + pix;
        for (int c = c0; c < CH; c += 4) {
            float v = xp[(size_t)c * HW];  // coalesced: lanes = consecutive pix
            float o;
            if (c == 0)      o = (sigm(v) + (float)wc) * STRIDE_F;
            else if (c == 1) o = (sigm(v) + (float)hc) * STRIDE_F;
            else if (c == 2) o = expf(v) * awc[a];
            else if (c == 3) o = expf(v) * ahc[a];
            else {
                o = sigm(v);
                if (c == 4) noobj_local += splus(v);  // -log(1-pconf)
            }
            lds[c * 65 + lc] = o;
        }
    }
    __syncthreads();

    // Phase 2: coalesced write of [cell][channel]-ordered output
    int nelem = ncells * CH;
    size_t obase = (size_t)(ba * HW + p0) * CH;
    for (int f = t; f < nelem; f += 256) {
        int cell = f / CH;
        int ch = f - cell * CH;
        out[obase + f] = lds[ch * 65 + cell];
    }

    // Reduce the noobj partial (only c0==0 threads are nonzero)
    for (int off = 32; off > 0; off >>= 1)
        noobj_local += __shfl_down(noobj_local, off, 64);
    if ((t & 63) == 0) red[t >> 6] = noobj_local;
    __syncthreads();
    if (t == 0) atomicAdd(&acc[0], red[0] + red[1] + red[2] + red[3]);
}

// ---------------------------------------------------------------------------
// Kernel C (gather): one wave per winner cell (blocks 0..255) gathers the 85
// channel values with lanes in parallel; blocks 256.. handle zeroed cells
// one per lane.  Latency is hidden by ~268 concurrent waves chip-wide.
// ---------------------------------------------------------------------------
__global__ __launch_bounds__(64) void gather_kernel(
        const float* __restrict__ x, const int* __restrict__ cnts,
        const int* __restrict__ wofs, const float* __restrict__ wtx,
        const float* __restrict__ wty, const float* __restrict__ wtw,
        const float* __restrict__ wth, const int* __restrict__ wlabel,
        const int* __restrict__ zofs, float* __restrict__ acc) {
    int b = blockIdx.x;
    int lane = threadIdx.x;
    if (b < NT) {
        if (b >= cnts[0]) return;          // beyond winner count
        int ofs = wofs[b];
        int label = wlabel[b];
        const float* xp = x + ofs;
        float lcls = 0.0f;
        {   // class channels 0..63
            float z = xp[(size_t)(5 + lane) * HW];
            lcls += (lane == label) ? splus(-z) : splus(z);
        }
        if (lane < 16) {                   // class channels 64..79
            int c = 64 + lane;
            float z = xp[(size_t)(5 + c) * HW];
            lcls += (c == label) ? splus(-z) : splus(z);
        }
        float other = 0.0f;
        if (lane == 0) {
            float z0 = xp[0];
            float z2 = xp[(size_t)2 * HW];
            float z4 = xp[(size_t)4 * HW];
            float cx = sigm(z0);
            float dx = cx - wtx[b], dy = cx - wty[b];   // ref bug: cx for y
            float dw = z2 - wtw[b], dh = z2 - wth[b];   // ref bug: pw for h
            other = dx*dx + dy*dy + dw*dw + dh*dh + splus(-z4);
        }
        for (int off = 32; off > 0; off >>= 1)
            lcls += __shfl_down(lcls, off, 64);
        if (lane == 0) {
            atomicAdd(&acc[1], other);
            atomicAdd(&acc[2], lcls);
        }
    } else {
        int idx = (b - NT) * 64 + lane;
        float v = 0.0f;
        if (idx < cnts[1]) v = splus(x[zofs[idx]]);
        for (int off = 32; off > 0; off >>= 1)
            v += __shfl_down(v, off, 64);
        if (lane == 0 && v != 0.0f) atomicAdd(&acc[3], v);
    }
}

// ---------------------------------------------------------------------------
// Kernel D (finalize): one thread combines the accumulator slots.
// ---------------------------------------------------------------------------
__global__ void finalize_kernel(const float* __restrict__ acc,
                                const int* __restrict__ cnts,
                                float* __restrict__ out_total) {
    if (threadIdx.x == 0 && blockIdx.x == 0) {
        float wc = (float)cnts[0];
        float n_obj = fmaxf(wc, 1.0f);
        float n_noobj = fmaxf((float)NCELLS - (float)cnts[1], 1.0f);
        float cls_den = fmaxf(80.0f * wc, 1.0f);
        float noobj_sum = acc[0] - acc[3];
        out_total[0] = acc[1] / n_obj + acc[2] / cls_den
                     + 0.5f * (noobj_sum / n_noobj);
    }
}

// ---------------------------------------------------------------------------
extern "C" void kernel_launch(void* const* d_in, const int* in_sizes, int n_in,
                              void* d_out, int out_size, void* d_ws, size_t ws_size,
                              hipStream_t stream) {
    (void)in_sizes; (void)n_in; (void)out_size; (void)ws_size;
    const float* x      = (const float*)d_in[0];
    const float* target = (const float*)d_in[1];
    float* out = (float*)d_out;

    char* ws = (char*)d_ws;
    float* acc    = (float*)(ws + 0);
    int*   cnts   = (int*)  (ws + 64);
    int*   wofs   = (int*)  (ws + 128);
    float* wtx    = (float*)(ws + 1152);
    float* wty    = (float*)(ws + 2176);
    float* wtw    = (float*)(ws + 3200);
    float* wth    = (float*)(ws + 4224);
    int*   wlabel = (int*)  (ws + 5248);
    int*   zofs   = (int*)  (ws + 6272);

    prep_kernel<<<1, 256, 0, stream>>>(target, acc, cnts, wofs, wtx, wty,
                                       wtw, wth, wlabel, zofs);
    dim3 grid(43, 48);
    main_kernel<<<grid, 256, 0, stream>>>(x, out, acc);
    gather_kernel<<<NT + (NT * 3 + 63) / 64, 64, 0, stream>>>(
        x, cnts, wofs, wtx, wty, wtw, wth, wlabel, zofs, acc);
    finalize_kernel<<<1, 64, 0, stream>>>(acc, cnts,
                                          out + (size_t)NB * NA * HW * CH);
}

// Round 4
// 120.984 us; speedup vs baseline: 2.9636x; 1.2885x over previous
//
#include <hip/hip_runtime.h>
#include <math.h>

// Problem constants (from reference)
#define NA 3
#define NC 80
#define CH 85              // NC+5
#define NB 16
#define HH 52
#define WW 52
#define HW 2704            // HH*WW
#define HWF4 676           // HW/4
#define NT 256             // num targets
#define NCELLS (NB*NA*HW)  // 129792
#define NBMW 4056          // bitmap words = ceil(NCELLS/32)
#define STRIDE_F 8.0f      // 416/52
#define IGN_THR 0.5f

// Main-kernel tiling: 104 pixels/block (26 float4), 2704 = 26*104 (no tail)
#define TP 104
#define TF4 26
#define NF4 2210           // CH * TF4 f4-elements per tile
#define LSTR 105           // LDS channel-row stride in words (odd: bank spread)
#define NBLK 1248          // 26 chunks * 48 (B*A)
#define NTAIL 269          // tail grid: 256 winners + 12 zero-blocks + 1 partial

__device__ __forceinline__ float sigm(float z) { return 1.0f / (1.0f + expf(-z)); }
// -log(sigmoid(z)) = log1p(exp(-z));  -log(1-sigmoid(z)) = log1p(exp(z))
__device__ __forceinline__ float splus(float z) { return log1pf(expf(z)); }

// ws layout (bytes):
//   0    : float acc[16]  acc[0]=dense noobj, acc[1]=obj xywh+conf,
//                         acc[2]=cls, acc[3]=zeroed-cell noobj correction
//   64   : int cnts[4]    {wcount, zcount, done, pad}
//   128  : int   wofs[256]
//   1152 : float wtx[256]
//   2176 : float wty[256]
//   3200 : float wtw[256]
//   4224 : float wth[256]
//   5248 : int   wlabel[256]
//   6272 : int   zofs[768]
//   9344 : float partials[1248]   (per-main-block dense noobj partial)
// total 14336 B

// ---------------------------------------------------------------------------
// Kernel 1 (fused): blocks 0..1247 do the dense transform (float4 in/out via
// LDS transpose) + per-block noobj partial; block 1248 does target prep
// (winner dedupe via fixed-trip LDS scan, zero-cell dedupe via LDS bitmap)
// and zeroes the accumulators/done counter.
// R3 lesson: 4 B/lane loads+stores left the kernel latency-bound at 16% of
// HBM peak -> vectorize to float4 and batch loads into registers first.
// ---------------------------------------------------------------------------
__global__ __launch_bounds__(256) void fused_kernel(
        const float* __restrict__ x, float* __restrict__ out,
        const float* __restrict__ target, float* __restrict__ acc,
        int* __restrict__ cnts, int* __restrict__ wofs,
        float* __restrict__ wtx, float* __restrict__ wty,
        float* __restrict__ wtw, float* __restrict__ wth,
        int* __restrict__ wlabel, int* __restrict__ zofs,
        float* __restrict__ partials) {
    __shared__ float lds[CH * LSTR];   // 35.7 KB; prep block aliases it
    __shared__ float red[4];
    int bid = blockIdx.x;
    int t = threadIdx.x;

    if (bid == NBLK) {
        // ---------------- prep block ----------------
        unsigned int* bm = (unsigned int*)lds;          // [NBMW]
        int* s_keyobj = (int*)lds + NBMW;               // [256]
        int* s_cnt = (int*)lds + NBMW + NT;             // {wcnt, zcnt}
        if (t < 16) acc[t] = 0.0f;
        if (t == 16) cnts[2] = 0;                       // done counter
        if (t == 0) { s_cnt[0] = 0; s_cnt[1] = 0; }
        for (int i = t; i < NBMW; i += 256) bm[i] = 0u;

        const float awc[3] = {10.f, 16.f, 33.f};
        const float ahc[3] = {13.f, 30.f, 23.f};
        float timg = target[t*6 + 0];
        float gxc  = target[t*6 + 1] * (float)WW;
        float gyc  = target[t*6 + 2] * (float)HH;
        float gw   = target[t*6 + 3] * (float)WW;
        float gh   = target[t*6 + 4] * (float)HH;
        int label  = (int)target[t*6 + 5];

        float best_iou = -1.0f;
        int best = 0, ignbits = 0;
        for (int a = 0; a < 3; a++) {
            float inter = fminf(awc[a], gw) * fminf(ahc[a], gh);
            float iou = inter / (awc[a]*ahc[a] + 1e-16f + gw*gh - inter);
            if (iou > best_iou) { best_iou = iou; best = a; }  // first-max
            if (iou > IGN_THR) ignbits |= (1 << a);
        }
        int img = (int)timg;
        int gi = (int)gxc, gj = (int)gyc;
        int pixel = gj * WW + gi;
        int cellbase = img * (NA * HW) + pixel;
        int keyobj = cellbase + best * HW;
        s_keyobj[t] = keyobj;
        __syncthreads();

        // winner iff no later target maps to same cell (fixed-trip scan:
        // independent LDS reads pipeline at throughput, not latency)
        bool dup = false;
        #pragma unroll 8
        for (int m = 0; m < NT; m++) {
            int k = s_keyobj[m];
            dup = dup || (m > t && k == keyobj);
        }
        if (!dup) {
            int p = atomicAdd(&s_cnt[0], 1);
            wofs[p] = (img * NA + best) * (CH * HW) + pixel;
            wtx[p] = gxc - floorf(gxc);
            wty[p] = gyc - floorf(gyc);
            wtw[p] = logf(gw / awc[best] + 1e-16f);
            wth[p] = logf(gh / ahc[best] + 1e-16f);
            wlabel[p] = label;
        }
        // distinct zeroed-noobj cells via bitmap (first setter appends)
        for (int a = 0; a < 3; a++) {
            bool flag = (a == best) || ((ignbits >> a) & 1);
            if (flag) {
                int key = cellbase + a * HW;
                unsigned int bit = 1u << (key & 31);
                unsigned int old = atomicOr(&bm[key >> 5], bit);
                if (!(old & bit)) {
                    int p = atomicAdd(&s_cnt[1], 1);
                    zofs[p] = ((img * NA + a) * CH + 4) * HW + pixel;
                }
            }
        }
        __syncthreads();
        if (t == 0) { cnts[0] = s_cnt[0]; cnts[1] = s_cnt[1]; }
        return;
    }

    // ---------------- dense transform block ----------------
    int chunk = bid % 26;            // pixel chunk (104 px)
    int ba    = bid / 26;            // b*3 + a
    int a     = ba % NA;
    const float awc[3] = {10.f, 16.f, 33.f};
    const float ahc[3] = {13.f, 30.f, 23.f};

    // Phase 1: batched float4 loads (all independent), then transform -> LDS
    const float4* x4 = (const float4*)x + (size_t)ba * (CH * HWF4)
                                        + chunk * TF4;
    float4 v[9];
    #pragma unroll
    for (int i = 0; i < 9; i++) {
        int idx = t + i * 256;
        if (idx < NF4) {
            int c = idx / TF4, q = idx - c * TF4;
            v[i] = x4[c * HWF4 + q];
        }
    }
    float noobj = 0.0f;
    #pragma unroll
    for (int i = 0; i < 9; i++) {
        int idx = t + i * 256;
        if (idx < NF4) {
            int c = idx / TF4, q = idx - c * TF4;
            float r[4] = {v[i].x, v[i].y, v[i].z, v[i].w};
            #pragma unroll
            for (int k = 0; k < 4; k++) {
                int l = q * 4 + k;               // local pixel 0..103
                float z = r[k], o;
                if (c == 0) {
                    int wc = l - ((l >= WW) ? WW : 0);
                    o = (sigm(z) + (float)wc) * STRIDE_F;
                } else if (c == 1) {
                    int hc = chunk * 2 + ((l >= WW) ? 1 : 0);
                    o = (sigm(z) + (float)hc) * STRIDE_F;
                } else if (c == 2) {
                    o = expf(z) * awc[a];
                } else if (c == 3) {
                    o = expf(z) * ahc[a];
                } else {
                    o = sigm(z);
                    if (c == 4) noobj += splus(z);
                }
                lds[c * LSTR + l] = o;
            }
        }
    }
    // reduce noobj partial across the block
    for (int off = 32; off > 0; off >>= 1)
        noobj += __shfl_down(noobj, off, 64);
    if ((t & 63) == 0) red[t >> 6] = noobj;
    __syncthreads();

    // Phase 2: float4 stores of [cell][channel]-ordered output
    float4* o4 = (float4*)out + (size_t)ba * (HW * CH / 4) + chunk * NF4;
    #pragma unroll
    for (int i = 0; i < 9; i++) {
        int j = t + i * 256;
        if (j < NF4) {
            int flat = 4 * j;
            int cell = flat / CH;            // local cell 0..103
            int ch = flat - cell * CH;
            float4 w;
            float* pw = &w.x;
            #pragma unroll
            for (int k = 0; k < 4; k++) {
                int chk = ch + k, cek = cell;
                if (chk >= CH) { chk -= CH; cek += 1; }
                pw[k] = lds[chk * LSTR + cek];
            }
            o4[j] = w;
        }
    }
    if (t == 0) partials[bid] = red[0] + red[1] + red[2] + red[3];
}

// ---------------------------------------------------------------------------
// Kernel 2 (tail): blocks 0..255 = winner gather; 256..267 = zero-cell noobj
// corrections; 268 = sum main-block partials. Last-finishing block (device-
// scope done counter + fences) combines accumulators and writes the scalar.
// ---------------------------------------------------------------------------
__global__ __launch_bounds__(64) void tail_kernel(
        const float* __restrict__ x, const int* __restrict__ cnts,
        const int* __restrict__ wofs, const float* __restrict__ wtx,
        const float* __restrict__ wty, const float* __restrict__ wtw,
        const float* __restrict__ wth, const int* __restrict__ wlabel,
        const int* __restrict__ zofs, const float* __restrict__ partials,
        float* __restrict__ acc, int* __restrict__ done,
        float* __restrict__ out_total) {
    int b = blockIdx.x;
    int lane = threadIdx.x;

    if (b < NT) {
        if (b < cnts[0]) {
            int ofs = wofs[b];
            int label = wlabel[b];
            const float* xp = x + ofs;
            float lcls;
            {   // class channels 0..63
                float z = xp[(size_t)(5 + lane) * HW];
                lcls = (lane == label) ? splus(-z) : splus(z);
            }
            if (lane < 16) {               // class channels 64..79
                int c = 64 + lane;
                float z = xp[(size_t)(5 + c) * HW];
                lcls += (c == label) ? splus(-z) : splus(z);
            }
            float other = 0.0f;
            if (lane == 0) {
                float z0 = xp[0];
                float z2 = xp[(size_t)2 * HW];
                float z4 = xp[(size_t)4 * HW];
                float cx = sigm(z0);
                float dx = cx - wtx[b], dy = cx - wty[b];  // ref bug: cx for y
                float dw = z2 - wtw[b], dh = z2 - wth[b];  // ref bug: pw for h
                other = dx*dx + dy*dy + dw*dw + dh*dh + splus(-z4);
            }
            for (int off = 32; off > 0; off >>= 1)
                lcls += __shfl_down(lcls, off, 64);
            if (lane == 0) {
                atomicAdd(&acc[1], other);
                atomicAdd(&acc[2], lcls);
            }
        }
    } else if (b < NT + 12) {
        int idx = (b - NT) * 64 + lane;
        float v = 0.0f;
        if (idx < cnts[1]) v = splus(x[zofs[idx]]);
        for (int off = 32; off > 0; off >>= 1)
            v += __shfl_down(v, off, 64);
        if (lane == 0) atomicAdd(&acc[3], v);
    } else {
        float s = 0.0f;
        for (int i = lane; i < NBLK; i += 64) s += partials[i];
        for (int off = 32; off > 0; off >>= 1)
            s += __shfl_down(s, off, 64);
        if (lane == 0) atomicAdd(&acc[0], s);
    }

    __threadfence();
    if (lane == 0) {
        int old = atomicAdd(done, 1);
        if (old == NTAIL - 1) {            // last block: finalize
            __threadfence();
            float a0 = atomicAdd(&acc[0], 0.0f);   // coherent reads
            float a1 = atomicAdd(&acc[1], 0.0f);
            float a2 = atomicAdd(&acc[2], 0.0f);
            float a3 = atomicAdd(&acc[3], 0.0f);
            float wc = (float)cnts[0];
            float n_obj = fmaxf(wc, 1.0f);
            float n_noobj = fmaxf((float)NCELLS - (float)cnts[1], 1.0f);
            float cls_den = fmaxf(80.0f * wc, 1.0f);
            out_total[0] = a1 / n_obj + a2 / cls_den
                         + 0.5f * ((a0 - a3) / n_noobj);
        }
    }
}

// ---------------------------------------------------------------------------
extern "C" void kernel_launch(void* const* d_in, const int* in_sizes, int n_in,
                              void* d_out, int out_size, void* d_ws, size_t ws_size,
                              hipStream_t stream) {
    (void)in_sizes; (void)n_in; (void)out_size; (void)ws_size;
    const float* x      = (const float*)d_in[0];
    const float* target = (const float*)d_in[1];
    float* out = (float*)d_out;

    char* ws = (char*)d_ws;
    float* acc      = (float*)(ws + 0);
    int*   cnts     = (int*)  (ws + 64);
    int*   wofs     = (int*)  (ws + 128);
    float* wtx      = (float*)(ws + 1152);
    float* wty      = (float*)(ws + 2176);
    float* wtw      = (float*)(ws + 3200);
    float* wth      = (float*)(ws + 4224);
    int*   wlabel   = (int*)  (ws + 5248);
    int*   zofs     = (int*)  (ws + 6272);
    float* partials = (float*)(ws + 9344);

    fused_kernel<<<NBLK + 1, 256, 0, stream>>>(
        x, out, target, acc, cnts, wofs, wtx, wty, wtw, wth, wlabel, zofs,
        partials);
    tail_kernel<<<NTAIL, 64, 0, stream>>>(
        x, cnts, wofs, wtx, wty, wtw, wth, wlabel, zofs, partials,
        acc, &cnts[2], out + (size_t)NB * NA * HW * CH);
}